// Round 1
// baseline (178.398 us; speedup 1.0000x reference)
//
#include <hip/hip_runtime.h>

#define J 17
#define F 128
#define TB 16          // batches per block (= MFMA M dim)
#define THREADS 256    // 4 waves; each wave owns 2 column tiles (done sequentially)

typedef __attribute__((ext_vector_type(4))) float f32x4;
typedef __attribute__((ext_vector_type(8))) short bf16x8;   // 8 bf16 in 4 VGPRs

// round-to-nearest-even f32 -> bf16 (branch-free; inputs are normal floats)
__device__ __forceinline__ unsigned short f2bf(float f) {
    unsigned u = __builtin_bit_cast(unsigned, f);
    u += 0x7fffu + ((u >> 16) & 1u);
    return (unsigned short)(u >> 16);
}

__device__ __forceinline__ f32x4 fma4(float a, f32x4 v, f32x4 c) {
#pragma unroll
    for (int r = 0; r < 4; ++r) c[r] = __builtin_fmaf(a, v[r], c[r]);
    return c;
}

// Precompute symmetrized A into workspace: wsA[0..288] = A_off (diag zeroed),
// wsA[289..305] = A_diag. Main kernel then reads these with uniform indices
// (scalar s_loads, K$-hot) instead of 289 LDS broadcasts per pass.
__global__ void prep_A(const float* __restrict__ adj, const float* __restrict__ adj2,
                       float* __restrict__ wsA) {
    for (int idx = threadIdx.x; idx < J * J; idx += 64) {
        int i = idx / J, j = idx % J;
        float a = 0.5f * (adj[i*J+j] + adj2[i*J+j] + adj[j*J+i] + adj2[j*J+i]);
        wsA[idx] = (i == j) ? 0.0f : a;
        if (i == j) wsA[J * J + i] = a;
    }
}

__global__ __launch_bounds__(THREADS, 2) void mgcn_kernel(
    const float* __restrict__ x, const float* __restrict__ W,
    const float* __restrict__ Mw, const float* __restrict__ bias,
    const float* __restrict__ wsA, float* __restrict__ out) {

    // x tile as bf16, layout byte = b*4352 + j*256 + k*2, XOR-swizzled by (b&7)<<4
    __shared__ __align__(16) unsigned char xs[TB * J * F * 2];   // 69632 B
    __shared__ float Ms[J * F];
    __shared__ float biasS[F];

    const int tid = threadIdx.x;
    const int b0  = blockIdx.x * TB;

    for (int idx = tid; idx < J * F; idx += THREADS) Ms[idx] = Mw[idx];
    if (tid < F) biasS[tid] = bias[tid];

    // ---- stage x: coalesced float4 reads, bf16 cvt, swizzled ds_write_b64 ----
    const float4* xg = (const float4*)(x + (size_t)b0 * (J * F));
    for (int it = 0; it < (TB * J * F / 4) / THREADS; ++it) {   // 34 iters
        int fi = it * THREADS + tid;
        float4 v = xg[fi];
        int b  = fi / (J * F / 4);          // /544
        int r  = fi % (J * F / 4);
        int j  = r / (F / 4);               // /32
        int k0 = (r % (F / 4)) * 4;
        unsigned byte = (unsigned)(b * (J * F * 2) + j * (F * 2) + k0 * 2);
        byte ^= (unsigned)((b & 7) << 4);   // same involution as the read side
        ushort4 u;
        u.x = f2bf(v.x); u.y = f2bf(v.y); u.z = f2bf(v.z); u.w = f2bf(v.w);
        *(ushort4*)(xs + byte) = u;
    }
    __syncthreads();

    const int wave = tid >> 6;
    const int lane = tid & 63;
    const int lrow = lane & 15;   // A-frag row (= local batch) and C/D column index
    const int lq   = lane >> 4;   // k-subchunk select / C/D row-group
    const float* __restrict__ Aoff  = wsA;
    const float* __restrict__ Adiag = wsA + J * J;

#pragma unroll 1
    for (int p = 0; p < 2; ++p) {
        const int ct   = wave * 2 + p;          // column tile 0..7
        const int gcol = ct * 16 + lrow;

        // W fragments for both matrices, kept in registers for the whole pass.
        // B-frag layout: n = lane&15 (gcol), k = ks*32 + lq*8 + e.
        union BF8 { bf16x8 v; unsigned short s[8]; };
        BF8 wf0[4], wf1[4];
#pragma unroll
        for (int ks = 0; ks < 4; ++ks) {
            const float* w0 = W + (size_t)(ks * 32 + lq * 8) * F + gcol;
            const float* w1 = w0 + F * F;
#pragma unroll
            for (int e = 0; e < 8; ++e) {
                wf0[ks].s[e] = f2bf(w0[e * F]);
                wf1[ks].s[e] = f2bf(w1[e * F]);
            }
        }

        const float bval = biasS[gcol];
        f32x4 acc[J];
#pragma unroll
        for (int i = 0; i < J; ++i) acc[i] = (f32x4){bval, bval, bval, bval};

        const unsigned rbase = (unsigned)(lrow * (J * F * 2));
        const unsigned swz   = (unsigned)((lrow & 7) << 4);

#pragma unroll
        for (int j = 0; j < J; ++j) {
            f32x4 h0 = {0.f, 0.f, 0.f, 0.f};
            f32x4 h1 = {0.f, 0.f, 0.f, 0.f};
#pragma unroll
            for (int ks = 0; ks < 4; ++ks) {
                unsigned byte = (rbase + (unsigned)(j * (F * 2) + ks * 64 + lq * 16)) ^ swz;
                bf16x8 af = __builtin_bit_cast(bf16x8, *(const uint4*)(xs + byte));
                h0 = __builtin_amdgcn_mfma_f32_16x16x32_bf16(af, wf0[ks].v, h0, 0, 0, 0);
                h1 = __builtin_amdgcn_mfma_f32_16x16x32_bf16(af, wf1[ks].v, h1, 0, 0, 0);
            }
            // out[b,i,g] += Adiag[j]*M[j,g]*h0   (i==j)
            //            +  Aoff[i,j]*M[j,g]*h1  (all i; Aoff diag is 0)
            float mj   = Ms[j * F + gcol];
            float admj = Adiag[j] * mj;
            f32x4 mh1;
#pragma unroll
            for (int r = 0; r < 4; ++r) mh1[r] = mj * h1[r];
            acc[j] = fma4(admj, h0, acc[j]);
#pragma unroll
            for (int i = 0; i < J; ++i)
                acc[i] = fma4(Aoff[i * J + j], mh1, acc[i]);
        }

        // epilogue: D layout col=lane&15 (g), row=lq*4+r (local batch)
#pragma unroll
        for (int i = 0; i < J; ++i) {
            size_t base = ((size_t)(b0 + lq * 4) * J + i) * F + gcol;
#pragma unroll
            for (int r = 0; r < 4; ++r)
                out[base + (size_t)r * (J * F)] = acc[i][r];
        }
    }
}

extern "C" void kernel_launch(void* const* d_in, const int* in_sizes, int n_in,
                              void* d_out, int out_size, void* d_ws, size_t ws_size,
                              hipStream_t stream) {
    const float* x    = (const float*)d_in[0];
    const float* W    = (const float*)d_in[1];
    const float* Mw   = (const float*)d_in[2];
    const float* adj  = (const float*)d_in[3];
    const float* adj2 = (const float*)d_in[4];
    const float* bias = (const float*)d_in[5];
    float* out = (float*)d_out;
    float* wsA = (float*)d_ws;   // needs (289+17)*4 = 1224 B

    int Btot = in_sizes[0] / (J * F);   // 16384
    prep_A<<<1, 64, 0, stream>>>(adj, adj2, wsA);
    mgcn_kernel<<<Btot / TB, THREADS, 0, stream>>>(x, W, Mw, bias, wsA, out);
}